// Round 11
// baseline (833.697 us; speedup 1.0000x reference)
//
#include <hip/hip_runtime.h>

#define D 128
#define CHUNK 2048
#define SPAD 36    // half-K row stride (32 + 4) for gemm

typedef unsigned int uint;
typedef unsigned short ushort;
typedef __attribute__((ext_vector_type(8))) short short8;
typedef __attribute__((ext_vector_type(4))) float floatx4;

// ---- bf16 helpers (manual, RNE) ----
__device__ __forceinline__ float bf_lo(uint u) { return __uint_as_float(u << 16); }
__device__ __forceinline__ float bf_hi(uint u) { return __uint_as_float(u & 0xffff0000u); }
__device__ __forceinline__ uint f2bf(float f) {
    uint x = __float_as_uint(f);
    return (x + 0x7fffu + ((x >> 16) & 1u)) >> 16;  // RNE
}

// ================= Setup: W converts + cursor init (merged) =================
__global__ void setup_kernel(const float* __restrict__ W1, const float* __restrict__ W2,
                             const float* __restrict__ W3, uint* __restrict__ Wt1,
                             uint* __restrict__ Wt2, uint* __restrict__ Wt3,
                             int* __restrict__ cursor, int NB, int CAP) {
    if (blockIdx.x < 96) {
        int gidx = blockIdx.x * 256 + threadIdx.x;   // 3 * 8192
        int w = gidx >> 13, rem = gidx & 8191;
        int n = rem >> 6, kp = rem & 63;
        const float* W = (w == 0) ? W1 : (w == 1) ? W2 : W3;
        uint* Wt = (w == 0) ? Wt1 : (w == 1) ? Wt2 : Wt3;
        Wt[(n << 6) + kp] = f2bf(W[(2 * kp) * 128 + n]) | (f2bf(W[(2 * kp + 1) * 128 + n]) << 16);
    } else {
        int b = threadIdx.x;
        if (b < NB) cursor[b] = b * CAP;
    }
}

// ================= Bucketed CSR build (single-pass bin, 512-node buckets) =================
__global__ void bin_kernel(const int* __restrict__ src, const int* __restrict__ dst,
                           int* __restrict__ cursor, uint* __restrict__ binned, int E) {
    __shared__ int cnt[256];
    __shared__ int wcur[256];
    int t = threadIdx.x;
    cnt[t] = 0;
    __syncthreads();
    int base = blockIdx.x * CHUNK + t;
    int dv[8]; uint sv[8];
#pragma unroll
    for (int i = 0; i < 8; i++) {
        int e = base + i * 256;
        int d = (e < E) ? dst[e] : -1;
        dv[i] = d;
        sv[i] = (e < E) ? (uint)src[e] : 0u;
        if (d >= 0) atomicAdd(&cnt[d >> 9], 1);
    }
    __syncthreads();
    {
        int c = cnt[t];
        wcur[t] = c ? atomicAdd(&cursor[t], c) : 0;
    }
    __syncthreads();
#pragma unroll
    for (int i = 0; i < 8; i++) {
        int d = dv[i];
        if (d >= 0) {
            int p = atomicAdd(&wcur[d >> 9], 1);
            binned[p] = sv[i] | ((uint)(d & 511) << 17);
        }
    }
}

__launch_bounds__(256)
__global__ void bucket_build_kernel(const uint* __restrict__ binned, const int* __restrict__ cursor,
                                    int* __restrict__ offs, int* __restrict__ oend,
                                    int* __restrict__ csr, float* __restrict__ dis,
                                    int N, int CAP) {
    __shared__ int hist[512];
    __shared__ int tsum[256];
    __shared__ int wcur[512];
    int b = blockIdx.x;
    int t = threadIdx.x;
    int s = b * CAP;
    int e = cursor[b];
    hist[t] = 0; hist[t + 256] = 0;
    __syncthreads();
    for (int i = s + t; i < e; i += 256)
        atomicAdd(&hist[(binned[i] >> 17) & 511], 1);
    __syncthreads();
    int h0 = t * 2;
    int v0 = hist[h0], v1 = hist[h0 + 1];
    int ts = v0 + v1;
    tsum[t] = ts;
    __syncthreads();
    for (int off = 1; off < 256; off <<= 1) {
        int x = (t >= off) ? tsum[t - off] : 0;
        __syncthreads();
        tsum[t] += x;
        __syncthreads();
    }
    int excl = tsum[t] - ts;
    int o0 = excl, o1 = o0 + v0;
    int n0 = (b << 9) + h0;
    wcur[h0] = s + o0; wcur[h0 + 1] = s + o1;
    if (n0 < N)     { offs[n0]     = s + o0; oend[n0]     = s + o0 + v0; dis[n0]     = rsqrtf((float)v0 + 1.0f); }
    if (n0 + 1 < N) { offs[n0 + 1] = s + o1; oend[n0 + 1] = s + o1 + v1; dis[n0 + 1] = rsqrtf((float)v1 + 1.0f); }
    __syncthreads();
    for (int i = s + t; i < e; i += 256) {
        uint en = binned[i];
        int local = (en >> 17) & 511;
        int p = atomicAdd(&wcur[local], 1);
        csr[p] = (int)(en & 0x1ffffu);
    }
}

// ================= MFMA GEMM: U = bf16( (A @ W) * dis[row] ) =================
// Software-pipelined: stage-1 A-tile prefetched into registers during stage-0 compute.
template <bool F32A>
__launch_bounds__(256)
__global__ void gemm_mfma_kernel(const void* __restrict__ Aptr, const uint* __restrict__ Wt,
                                 const float* __restrict__ dis, uint* __restrict__ U, int N) {
    __shared__ uint lds[128 * SPAD * 2];
    uint* a_lds = lds;
    uint* w_lds = lds + 128 * SPAD;
    int tid = threadIdx.x;
    int m0 = blockIdx.x * 128;
    int wave = tid >> 6, lane = tid & 63;
    int lm = lane & 15, quad = lane >> 4;

    floatx4 acc[2][8];
#pragma unroll
    for (int i = 0; i < 2; i++)
#pragma unroll
        for (int j = 0; j < 8; j++)
            acc[i][j] = (floatx4){0.f, 0.f, 0.f, 0.f};

    // ---- stage 0: A(ks=0), W(ks=0) -> LDS
    if (F32A) {
        const float* Af = (const float*)Aptr;
#pragma unroll
        for (int i = 0; i < 8; i++) {
            int gi = tid + i * 256;           // 2048 = 128 rows x 16 float4
            int row = gi >> 4, j = gi & 15;
            int grow = m0 + row;
            float4 v = (grow < N) ? *(const float4*)&Af[(size_t)grow * 128 + j * 4]
                                  : make_float4(0.f, 0.f, 0.f, 0.f);
            uint2 o;
            o.x = f2bf(v.x) | (f2bf(v.y) << 16);
            o.y = f2bf(v.z) | (f2bf(v.w) << 16);
            *(uint2*)&a_lds[row * SPAD + j * 2] = o;
        }
    } else {
        const uint* Ab = (const uint*)Aptr;
#pragma unroll
        for (int i = 0; i < 4; i++) {
            int gi = tid + i * 256;           // 1024 = 128 rows x 8 uint4
            int row = gi >> 3, c4 = (gi & 7) << 2;
            int grow = m0 + row;
            uint4 av = (grow < N) ? *(const uint4*)&Ab[(size_t)grow * 64 + c4]
                                  : make_uint4(0u, 0u, 0u, 0u);
            *(uint4*)&a_lds[row * SPAD + c4] = av;
        }
    }
#pragma unroll
    for (int i = 0; i < 4; i++) {
        int gi = tid + i * 256;
        int row = gi >> 3, c4 = (gi & 7) << 2;
        *(uint4*)&w_lds[row * SPAD + c4] = *(const uint4*)&Wt[(size_t)row * 64 + c4];
    }
    __syncthreads();

    // ---- prefetch stage-1 A into registers
    float4 pf_f[8];
    uint4 pf_u[4];
    if (F32A) {
        const float* Af = (const float*)Aptr;
#pragma unroll
        for (int i = 0; i < 8; i++) {
            int gi = tid + i * 256;
            int row = gi >> 4, j = gi & 15;
            int grow = m0 + row;
            pf_f[i] = (grow < N) ? *(const float4*)&Af[(size_t)grow * 128 + 64 + j * 4]
                                 : make_float4(0.f, 0.f, 0.f, 0.f);
        }
    } else {
        const uint* Ab = (const uint*)Aptr;
#pragma unroll
        for (int i = 0; i < 4; i++) {
            int gi = tid + i * 256;
            int row = gi >> 3, c4 = (gi & 7) << 2;
            int grow = m0 + row;
            pf_u[i] = (grow < N) ? *(const uint4*)&Ab[(size_t)grow * 64 + 32 + c4]
                                 : make_uint4(0u, 0u, 0u, 0u);
        }
    }

    // ---- compute stage 0
#pragma unroll
    for (int kc = 0; kc < 2; kc++) {
        int ko = kc * 16 + quad * 4;
        short8 b[8];
#pragma unroll
        for (int nt = 0; nt < 8; nt++)
            b[nt] = *(short8*)&w_lds[(nt * 16 + lm) * SPAD + ko];
        short8 a0 = *(short8*)&a_lds[(wave * 32 + lm) * SPAD + ko];
        short8 a1 = *(short8*)&a_lds[(wave * 32 + 16 + lm) * SPAD + ko];
#pragma unroll
        for (int nt = 0; nt < 8; nt++) {
            acc[0][nt] = __builtin_amdgcn_mfma_f32_16x16x32_bf16(a0, b[nt], acc[0][nt], 0, 0, 0);
            acc[1][nt] = __builtin_amdgcn_mfma_f32_16x16x32_bf16(a1, b[nt], acc[1][nt], 0, 0, 0);
        }
    }
    __syncthreads();

    // ---- stage 1: regs -> LDS; W(ks=1) -> LDS
    if (F32A) {
#pragma unroll
        for (int i = 0; i < 8; i++) {
            int gi = tid + i * 256;
            int row = gi >> 4, j = gi & 15;
            uint2 o;
            o.x = f2bf(pf_f[i].x) | (f2bf(pf_f[i].y) << 16);
            o.y = f2bf(pf_f[i].z) | (f2bf(pf_f[i].w) << 16);
            *(uint2*)&a_lds[row * SPAD + j * 2] = o;
        }
    } else {
#pragma unroll
        for (int i = 0; i < 4; i++) {
            int gi = tid + i * 256;
            int row = gi >> 3, c4 = (gi & 7) << 2;
            *(uint4*)&a_lds[row * SPAD + c4] = pf_u[i];
        }
    }
#pragma unroll
    for (int i = 0; i < 4; i++) {
        int gi = tid + i * 256;
        int row = gi >> 3, c4 = (gi & 7) << 2;
        *(uint4*)&w_lds[row * SPAD + c4] = *(const uint4*)&Wt[(size_t)row * 64 + 32 + c4];
    }
    __syncthreads();

    // ---- compute stage 1
#pragma unroll
    for (int kc = 0; kc < 2; kc++) {
        int ko = kc * 16 + quad * 4;
        short8 b[8];
#pragma unroll
        for (int nt = 0; nt < 8; nt++)
            b[nt] = *(short8*)&w_lds[(nt * 16 + lm) * SPAD + ko];
        short8 a0 = *(short8*)&a_lds[(wave * 32 + lm) * SPAD + ko];
        short8 a1 = *(short8*)&a_lds[(wave * 32 + 16 + lm) * SPAD + ko];
#pragma unroll
        for (int nt = 0; nt < 8; nt++) {
            acc[0][nt] = __builtin_amdgcn_mfma_f32_16x16x32_bf16(a0, b[nt], acc[0][nt], 0, 0, 0);
            acc[1][nt] = __builtin_amdgcn_mfma_f32_16x16x32_bf16(a1, b[nt], acc[1][nt], 0, 0, 0);
        }
    }
    __syncthreads();

    // ---- epilogue: scale by dis, pack bf16, LDS bounce, coalesced store
    ushort* o_lds = (ushort*)lds;  // [128][132]
    float dv[2][4];
#pragma unroll
    for (int ms = 0; ms < 2; ms++)
#pragma unroll
        for (int r = 0; r < 4; r++) {
            int row = m0 + wave * 32 + ms * 16 + quad * 4 + r;
            dv[ms][r] = (row < N) ? dis[row] : 0.f;
        }
#pragma unroll
    for (int ms = 0; ms < 2; ms++)
#pragma unroll
        for (int nt = 0; nt < 8; nt++)
#pragma unroll
            for (int r = 0; r < 4; r++) {
                int row = wave * 32 + ms * 16 + quad * 4 + r;
                int col = nt * 16 + lm;
                o_lds[row * 132 + col] = (ushort)f2bf(acc[ms][nt][r] * dv[ms][r]);
            }
    __syncthreads();
#pragma unroll
    for (int i = 0; i < 16; i++) {
        int gi = tid + i * 256;
        int row = gi >> 5, c2 = gi & 31;
        int grow = m0 + row;
        if (grow < N) {
            uint2 v = *(uint2*)&lds[row * 66 + c2 * 2];
            *(uint2*)&U[(size_t)grow * 64 + c2 * 2] = v;
        }
    }
}

// ================= Aggregation v2: 16 lanes/edge, 4 edges per VMEM instr =================
__launch_bounds__(256)
__global__ void aggregate_kernel(const uint* __restrict__ U, const int* __restrict__ offs,
                                 const int* __restrict__ oend, const int* __restrict__ csr_src,
                                 const float* __restrict__ dis, const float* __restrict__ bias,
                                 uint* __restrict__ H, int N) {
    int wave = threadIdx.x >> 6;
    int lane = threadIdx.x & 63;
    int n = blockIdx.x * 4 + wave;
    if (n >= N) return;
    int g = lane >> 4, i16 = lane & 15;

    float a0 = 0.f, a1 = 0.f, a2 = 0.f, a3 = 0.f, a4 = 0.f, a5 = 0.f, a6 = 0.f, a7 = 0.f;
    int s = offs[n], e = oend[n];
    int j = s + g;
    for (; j + 12 < e; j += 16) {
        int s0 = csr_src[j], s1 = csr_src[j + 4], s2 = csr_src[j + 8], s3 = csr_src[j + 12];
        uint4 u0 = *(const uint4*)&U[(size_t)s0 * 64 + i16 * 4];
        uint4 u1 = *(const uint4*)&U[(size_t)s1 * 64 + i16 * 4];
        uint4 u2 = *(const uint4*)&U[(size_t)s2 * 64 + i16 * 4];
        uint4 u3 = *(const uint4*)&U[(size_t)s3 * 64 + i16 * 4];
        a0 += bf_lo(u0.x) + bf_lo(u1.x) + bf_lo(u2.x) + bf_lo(u3.x);
        a1 += bf_hi(u0.x) + bf_hi(u1.x) + bf_hi(u2.x) + bf_hi(u3.x);
        a2 += bf_lo(u0.y) + bf_lo(u1.y) + bf_lo(u2.y) + bf_lo(u3.y);
        a3 += bf_hi(u0.y) + bf_hi(u1.y) + bf_hi(u2.y) + bf_hi(u3.y);
        a4 += bf_lo(u0.z) + bf_lo(u1.z) + bf_lo(u2.z) + bf_lo(u3.z);
        a5 += bf_hi(u0.z) + bf_hi(u1.z) + bf_hi(u2.z) + bf_hi(u3.z);
        a6 += bf_lo(u0.w) + bf_lo(u1.w) + bf_lo(u2.w) + bf_lo(u3.w);
        a7 += bf_hi(u0.w) + bf_hi(u1.w) + bf_hi(u2.w) + bf_hi(u3.w);
    }
    for (; j < e; j += 4) {
        int s0 = csr_src[j];
        uint4 u = *(const uint4*)&U[(size_t)s0 * 64 + i16 * 4];
        a0 += bf_lo(u.x); a1 += bf_hi(u.x);
        a2 += bf_lo(u.y); a3 += bf_hi(u.y);
        a4 += bf_lo(u.z); a5 += bf_hi(u.z);
        a6 += bf_lo(u.w); a7 += bf_hi(u.w);
    }
    a0 += __shfl_xor(a0, 16); a0 += __shfl_xor(a0, 32);
    a1 += __shfl_xor(a1, 16); a1 += __shfl_xor(a1, 32);
    a2 += __shfl_xor(a2, 16); a2 += __shfl_xor(a2, 32);
    a3 += __shfl_xor(a3, 16); a3 += __shfl_xor(a3, 32);
    a4 += __shfl_xor(a4, 16); a4 += __shfl_xor(a4, 32);
    a5 += __shfl_xor(a5, 16); a5 += __shfl_xor(a5, 32);
    a6 += __shfl_xor(a6, 16); a6 += __shfl_xor(a6, 32);
    a7 += __shfl_xor(a7, 16); a7 += __shfl_xor(a7, 32);

    if (g == 0) {
        uint4 su = *(const uint4*)&U[(size_t)n * 64 + i16 * 4];
        a0 += bf_lo(su.x); a1 += bf_hi(su.x);
        a2 += bf_lo(su.y); a3 += bf_hi(su.y);
        a4 += bf_lo(su.z); a5 += bf_hi(su.z);
        a6 += bf_lo(su.w); a7 += bf_hi(su.w);
        float dn = dis[n];
        float4 b0 = *(const float4*)&bias[i16 * 8];
        float4 b1 = *(const float4*)&bias[i16 * 8 + 4];
        uint4 o;
        o.x = f2bf(fmaxf(fmaf(a0, dn, b0.x), 0.f)) | (f2bf(fmaxf(fmaf(a1, dn, b0.y), 0.f)) << 16);
        o.y = f2bf(fmaxf(fmaf(a2, dn, b0.z), 0.f)) | (f2bf(fmaxf(fmaf(a3, dn, b0.w), 0.f)) << 16);
        o.z = f2bf(fmaxf(fmaf(a4, dn, b1.x), 0.f)) | (f2bf(fmaxf(fmaf(a5, dn, b1.y), 0.f)) << 16);
        o.w = f2bf(fmaxf(fmaf(a6, dn, b1.z), 0.f)) | (f2bf(fmaxf(fmaf(a7, dn, b1.w), 0.f)) << 16);
        *(uint4*)&H[(size_t)n * 64 + i16 * 4] = o;
    }
}

// ================= Fused layer-3 aggregation + pool accumulation =================
// Same gather as aggregate_kernel, but instead of writing H, atomically accumulates
// the fp32 row into pooled[batch[n]][128] (L2-resident, 256 KB).
__launch_bounds__(256)
__global__ void aggregate_pool_kernel(const uint* __restrict__ U, const int* __restrict__ offs,
                                      const int* __restrict__ oend, const int* __restrict__ csr_src,
                                      const float* __restrict__ dis, const float* __restrict__ bias,
                                      const int* __restrict__ batch, float* __restrict__ pooled,
                                      int N) {
    int wave = threadIdx.x >> 6;
    int lane = threadIdx.x & 63;
    int n = blockIdx.x * 4 + wave;
    if (n >= N) return;
    int g = lane >> 4, i16 = lane & 15;

    float a0 = 0.f, a1 = 0.f, a2 = 0.f, a3 = 0.f, a4 = 0.f, a5 = 0.f, a6 = 0.f, a7 = 0.f;
    int s = offs[n], e = oend[n];
    int j = s + g;
    for (; j + 12 < e; j += 16) {
        int s0 = csr_src[j], s1 = csr_src[j + 4], s2 = csr_src[j + 8], s3 = csr_src[j + 12];
        uint4 u0 = *(const uint4*)&U[(size_t)s0 * 64 + i16 * 4];
        uint4 u1 = *(const uint4*)&U[(size_t)s1 * 64 + i16 * 4];
        uint4 u2 = *(const uint4*)&U[(size_t)s2 * 64 + i16 * 4];
        uint4 u3 = *(const uint4*)&U[(size_t)s3 * 64 + i16 * 4];
        a0 += bf_lo(u0.x) + bf_lo(u1.x) + bf_lo(u2.x) + bf_lo(u3.x);
        a1 += bf_hi(u0.x) + bf_hi(u1.x) + bf_hi(u2.x) + bf_hi(u3.x);
        a2 += bf_lo(u0.y) + bf_lo(u1.y) + bf_lo(u2.y) + bf_lo(u3.y);
        a3 += bf_hi(u0.y) + bf_hi(u1.y) + bf_hi(u2.y) + bf_hi(u3.y);
        a4 += bf_lo(u0.z) + bf_lo(u1.z) + bf_lo(u2.z) + bf_lo(u3.z);
        a5 += bf_hi(u0.z) + bf_hi(u1.z) + bf_hi(u2.z) + bf_hi(u3.z);
        a6 += bf_lo(u0.w) + bf_lo(u1.w) + bf_lo(u2.w) + bf_lo(u3.w);
        a7 += bf_hi(u0.w) + bf_hi(u1.w) + bf_hi(u2.w) + bf_hi(u3.w);
    }
    for (; j < e; j += 4) {
        int s0 = csr_src[j];
        uint4 u = *(const uint4*)&U[(size_t)s0 * 64 + i16 * 4];
        a0 += bf_lo(u.x); a1 += bf_hi(u.x);
        a2 += bf_lo(u.y); a3 += bf_hi(u.y);
        a4 += bf_lo(u.z); a5 += bf_hi(u.z);
        a6 += bf_lo(u.w); a7 += bf_hi(u.w);
    }
    a0 += __shfl_xor(a0, 16); a0 += __shfl_xor(a0, 32);
    a1 += __shfl_xor(a1, 16); a1 += __shfl_xor(a1, 32);
    a2 += __shfl_xor(a2, 16); a2 += __shfl_xor(a2, 32);
    a3 += __shfl_xor(a3, 16); a3 += __shfl_xor(a3, 32);
    a4 += __shfl_xor(a4, 16); a4 += __shfl_xor(a4, 32);
    a5 += __shfl_xor(a5, 16); a5 += __shfl_xor(a5, 32);
    a6 += __shfl_xor(a6, 16); a6 += __shfl_xor(a6, 32);
    a7 += __shfl_xor(a7, 16); a7 += __shfl_xor(a7, 32);

    if (g == 0) {
        uint4 su = *(const uint4*)&U[(size_t)n * 64 + i16 * 4];
        a0 += bf_lo(su.x); a1 += bf_hi(su.x);
        a2 += bf_lo(su.y); a3 += bf_hi(su.y);
        a4 += bf_lo(su.z); a5 += bf_hi(su.z);
        a6 += bf_lo(su.w); a7 += bf_hi(su.w);
        float dn = dis[n];
        float4 b0 = *(const float4*)&bias[i16 * 8];
        float4 b1 = *(const float4*)&bias[i16 * 8 + 4];
        float h0 = fmaxf(fmaf(a0, dn, b0.x), 0.f);
        float h1 = fmaxf(fmaf(a1, dn, b0.y), 0.f);
        float h2 = fmaxf(fmaf(a2, dn, b0.z), 0.f);
        float h3 = fmaxf(fmaf(a3, dn, b0.w), 0.f);
        float h4 = fmaxf(fmaf(a4, dn, b1.x), 0.f);
        float h5 = fmaxf(fmaf(a5, dn, b1.y), 0.f);
        float h6 = fmaxf(fmaf(a6, dn, b1.z), 0.f);
        float h7 = fmaxf(fmaf(a7, dn, b1.w), 0.f);
        float* pp = &pooled[(size_t)batch[n] * 128 + i16 * 8];
        atomicAdd(pp + 0, h0); atomicAdd(pp + 1, h1);
        atomicAdd(pp + 2, h2); atomicAdd(pp + 3, h3);
        atomicAdd(pp + 4, h4); atomicAdd(pp + 5, h5);
        atomicAdd(pp + 6, h6); atomicAdd(pp + 7, h7);
    }
}

// ================= Final FC: out[g] = (pooled[g]/cnt[g]) @ Wfc + bfc =================
__launch_bounds__(128)
__global__ void fc_kernel(const float* __restrict__ pooled, const int* __restrict__ batch,
                          const float* __restrict__ Wfc, const float* __restrict__ bfc,
                          float* __restrict__ out, int N) {
    __shared__ float red[2];
    int g = blockIdx.x;
    int c = threadIdx.x;   // 128

    int lo = 0, hi = N;
    while (lo < hi) { int mid = (lo + hi) >> 1; if (batch[mid] < g) lo = mid + 1; else hi = mid; }
    int st = lo;
    hi = N;
    while (lo < hi) { int mid = (lo + hi) >> 1; if (batch[mid] < g + 1) lo = mid + 1; else hi = mid; }
    int en = lo;

    float cnt = fmaxf((float)(en - st), 1.0f);
    float p = (pooled[(size_t)g * 128 + c] / cnt) * Wfc[c];
    for (int off = 32; off > 0; off >>= 1) p += __shfl_down(p, off);
    if ((c & 63) == 0) red[c >> 6] = p;
    __syncthreads();
    if (c == 0) out[g] = red[0] + red[1] + bfc[0];
}

extern "C" void kernel_launch(void* const* d_in, const int* in_sizes, int n_in,
                              void* d_out, int out_size, void* d_ws, size_t ws_size,
                              hipStream_t stream) {
    const float* x   = (const float*)d_in[0];
    const int* eidx  = (const int*)d_in[1];
    const int* batch = (const int*)d_in[2];
    const float* W1  = (const float*)d_in[3];
    const float* b1  = (const float*)d_in[4];
    const float* W2  = (const float*)d_in[5];
    const float* b2  = (const float*)d_in[6];
    const float* W3  = (const float*)d_in[7];
    const float* b3  = (const float*)d_in[8];
    const float* Wfc = (const float*)d_in[9];
    const float* bfc = (const float*)d_in[10];
    float* out = (float*)d_out;

    int N = in_sizes[2];
    int E = in_sizes[1] / 2;
    int G = out_size;
    int NB = (N + 511) >> 9;                   // <= 256
    int CAP = E / NB + 1536;                   // per-bucket window (~16 sigma slack)

    const int* src = eidx;
    const int* dst = eidx + E;

    char* ws = (char*)d_ws;
    size_t off = 0;
    auto alloc = [&](size_t bytes) -> void* {
        void* p = ws + off;
        off += (bytes + 255) & ~(size_t)255;
        return p;
    };
    size_t winsz = (size_t)NB * CAP;
    uint* Ua     = (uint*)alloc((size_t)N * 64 * sizeof(uint));   // bf16 [N,128]
    uint* Ub     = (uint*)alloc((size_t)N * 64 * sizeof(uint));   // bf16 [N,128]
    uint* Wt1    = (uint*)alloc(8192 * sizeof(uint));
    uint* Wt2    = (uint*)alloc(8192 * sizeof(uint));
    uint* Wt3    = (uint*)alloc(8192 * sizeof(uint));
    float* dis   = (float*)alloc((size_t)N * sizeof(float));
    int* offs    = (int*)alloc((size_t)N * sizeof(int));
    int* oend    = (int*)alloc((size_t)N * sizeof(int));
    int* csr     = (int*)alloc(winsz * sizeof(int));
    uint* binned = (uint*)alloc(winsz * sizeof(uint));
    int* cursor  = (int*)alloc(256 * sizeof(int));
    float* pooled = (float*)alloc((size_t)G * 128 * sizeof(float));
    (void)ws_size; (void)n_in;

    hipMemsetAsync(pooled, 0, (size_t)G * 128 * sizeof(float), stream);

    int cb = (E + CHUNK - 1) / CHUNK;

    setup_kernel<<<97, 256, 0, stream>>>(W1, W2, W3, Wt1, Wt2, Wt3, cursor, NB, CAP);
    bin_kernel<<<cb, 256, 0, stream>>>(src, dst, cursor, binned, E);
    bucket_build_kernel<<<NB, 256, 0, stream>>>(binned, cursor, offs, oend, csr, dis, N, CAP);

    int gb = (N + 127) / 128;
    int ab = (N + 3) / 4;

    gemm_mfma_kernel<true><<<gb, 256, 0, stream>>>(x, Wt1, dis, Ua, N);
    aggregate_kernel<<<ab, 256, 0, stream>>>(Ua, offs, oend, csr, dis, b1, Ub, N);
    gemm_mfma_kernel<false><<<gb, 256, 0, stream>>>(Ub, Wt2, dis, Ua, N);
    aggregate_kernel<<<ab, 256, 0, stream>>>(Ua, offs, oend, csr, dis, b2, Ub, N);
    gemm_mfma_kernel<false><<<gb, 256, 0, stream>>>(Ub, Wt3, dis, Ua, N);
    aggregate_pool_kernel<<<ab, 256, 0, stream>>>(Ua, offs, oend, csr, dis, b3, batch, pooled, N);
    fc_kernel<<<G, 128, 0, stream>>>(pooled, batch, Wfc, bfc, out, N);
}

// Round 12
// 406.548 us; speedup vs baseline: 2.0507x; 2.0507x over previous
//
#include <hip/hip_runtime.h>

#define D 128
#define CHUNK 4096
#define SPAD 36    // half-K row stride (32 + 4) for gemm

typedef unsigned int uint;
typedef unsigned short ushort;
typedef __attribute__((ext_vector_type(8))) short short8;
typedef __attribute__((ext_vector_type(4))) float floatx4;

// ---- bf16 helpers (manual, RNE) ----
__device__ __forceinline__ float bf_lo(uint u) { return __uint_as_float(u << 16); }
__device__ __forceinline__ float bf_hi(uint u) { return __uint_as_float(u & 0xffff0000u); }
__device__ __forceinline__ uint f2bf(float f) {
    uint x = __float_as_uint(f);
    return (x + 0x7fffu + ((x >> 16) & 1u)) >> 16;  // RNE
}

// ================= Setup: W converts + cursor init (merged) =================
__global__ void setup_kernel(const float* __restrict__ W1, const float* __restrict__ W2,
                             const float* __restrict__ W3, uint* __restrict__ Wt1,
                             uint* __restrict__ Wt2, uint* __restrict__ Wt3,
                             int* __restrict__ cursor, int NB, int CAP) {
    if (blockIdx.x < 96) {
        int gidx = blockIdx.x * 256 + threadIdx.x;   // 3 * 8192
        int w = gidx >> 13, rem = gidx & 8191;
        int n = rem >> 6, kp = rem & 63;
        const float* W = (w == 0) ? W1 : (w == 1) ? W2 : W3;
        uint* Wt = (w == 0) ? Wt1 : (w == 1) ? Wt2 : Wt3;
        Wt[(n << 6) + kp] = f2bf(W[(2 * kp) * 128 + n]) | (f2bf(W[(2 * kp + 1) * 128 + n]) << 16);
    } else {
        int b = threadIdx.x;
        if (b < NB) cursor[b] = b * CAP;
    }
}

// ================= Bucketed CSR build (single-pass bin, 512-node buckets) =================
__global__ void bin_kernel(const int* __restrict__ src, const int* __restrict__ dst,
                           int* __restrict__ cursor, uint* __restrict__ binned, int E) {
    __shared__ int cnt[256];
    __shared__ int wcur[256];
    int t = threadIdx.x;
    cnt[t] = 0;
    __syncthreads();
    int base = blockIdx.x * CHUNK + t;
    int dv[16]; uint sv[16];
#pragma unroll
    for (int i = 0; i < 16; i++) {
        int e = base + i * 256;
        int d = (e < E) ? dst[e] : -1;
        dv[i] = d;
        sv[i] = (e < E) ? (uint)src[e] : 0u;
        if (d >= 0) atomicAdd(&cnt[d >> 9], 1);
    }
    __syncthreads();
    {
        int c = cnt[t];
        wcur[t] = c ? atomicAdd(&cursor[t], c) : 0;
    }
    __syncthreads();
#pragma unroll
    for (int i = 0; i < 16; i++) {
        int d = dv[i];
        if (d >= 0) {
            int p = atomicAdd(&wcur[d >> 9], 1);
            binned[p] = sv[i] | ((uint)(d & 511) << 17);
        }
    }
}

__launch_bounds__(256)
__global__ void bucket_build_kernel(const uint* __restrict__ binned, const int* __restrict__ cursor,
                                    int* __restrict__ offs, int* __restrict__ oend,
                                    int* __restrict__ csr, float* __restrict__ dis,
                                    int N, int CAP) {
    __shared__ int hist[512];
    __shared__ int tsum[256];
    __shared__ int wcur[512];
    int b = blockIdx.x;
    int t = threadIdx.x;
    int s = b * CAP;
    int e = cursor[b];
    hist[t] = 0; hist[t + 256] = 0;
    __syncthreads();
    for (int i = s + t; i < e; i += 256)
        atomicAdd(&hist[(binned[i] >> 17) & 511], 1);
    __syncthreads();
    int h0 = t * 2;
    int v0 = hist[h0], v1 = hist[h0 + 1];
    int ts = v0 + v1;
    tsum[t] = ts;
    __syncthreads();
    for (int off = 1; off < 256; off <<= 1) {
        int x = (t >= off) ? tsum[t - off] : 0;
        __syncthreads();
        tsum[t] += x;
        __syncthreads();
    }
    int excl = tsum[t] - ts;
    int o0 = excl, o1 = o0 + v0;
    int n0 = (b << 9) + h0;
    wcur[h0] = s + o0; wcur[h0 + 1] = s + o1;
    if (n0 < N)     { offs[n0]     = s + o0; oend[n0]     = s + o0 + v0; dis[n0]     = rsqrtf((float)v0 + 1.0f); }
    if (n0 + 1 < N) { offs[n0 + 1] = s + o1; oend[n0 + 1] = s + o1 + v1; dis[n0 + 1] = rsqrtf((float)v1 + 1.0f); }
    __syncthreads();
    for (int i = s + t; i < e; i += 256) {
        uint en = binned[i];
        int local = (en >> 17) & 511;
        int p = atomicAdd(&wcur[local], 1);
        csr[p] = (int)(en & 0x1ffffu);
    }
}

// ================= MFMA GEMM: U = bf16( (A @ W) * dis[row] ) =================
// Software-pipelined: stage-1 A-tile prefetched into registers during stage-0 compute.
template <bool F32A>
__launch_bounds__(256)
__global__ void gemm_mfma_kernel(const void* __restrict__ Aptr, const uint* __restrict__ Wt,
                                 const float* __restrict__ dis, uint* __restrict__ U, int N) {
    __shared__ uint lds[128 * SPAD * 2];
    uint* a_lds = lds;
    uint* w_lds = lds + 128 * SPAD;
    int tid = threadIdx.x;
    int m0 = blockIdx.x * 128;
    int wave = tid >> 6, lane = tid & 63;
    int lm = lane & 15, quad = lane >> 4;

    floatx4 acc[2][8];
#pragma unroll
    for (int i = 0; i < 2; i++)
#pragma unroll
        for (int j = 0; j < 8; j++)
            acc[i][j] = (floatx4){0.f, 0.f, 0.f, 0.f};

    // ---- stage 0: A(ks=0), W(ks=0) -> LDS
    if (F32A) {
        const float* Af = (const float*)Aptr;
#pragma unroll
        for (int i = 0; i < 8; i++) {
            int gi = tid + i * 256;           // 2048 = 128 rows x 16 float4
            int row = gi >> 4, j = gi & 15;
            int grow = m0 + row;
            float4 v = (grow < N) ? *(const float4*)&Af[(size_t)grow * 128 + j * 4]
                                  : make_float4(0.f, 0.f, 0.f, 0.f);
            uint2 o;
            o.x = f2bf(v.x) | (f2bf(v.y) << 16);
            o.y = f2bf(v.z) | (f2bf(v.w) << 16);
            *(uint2*)&a_lds[row * SPAD + j * 2] = o;
        }
    } else {
        const uint* Ab = (const uint*)Aptr;
#pragma unroll
        for (int i = 0; i < 4; i++) {
            int gi = tid + i * 256;           // 1024 = 128 rows x 8 uint4
            int row = gi >> 3, c4 = (gi & 7) << 2;
            int grow = m0 + row;
            uint4 av = (grow < N) ? *(const uint4*)&Ab[(size_t)grow * 64 + c4]
                                  : make_uint4(0u, 0u, 0u, 0u);
            *(uint4*)&a_lds[row * SPAD + c4] = av;
        }
    }
#pragma unroll
    for (int i = 0; i < 4; i++) {
        int gi = tid + i * 256;
        int row = gi >> 3, c4 = (gi & 7) << 2;
        *(uint4*)&w_lds[row * SPAD + c4] = *(const uint4*)&Wt[(size_t)row * 64 + c4];
    }
    __syncthreads();

    // ---- prefetch stage-1 A into registers
    float4 pf_f[8];
    uint4 pf_u[4];
    if (F32A) {
        const float* Af = (const float*)Aptr;
#pragma unroll
        for (int i = 0; i < 8; i++) {
            int gi = tid + i * 256;
            int row = gi >> 4, j = gi & 15;
            int grow = m0 + row;
            pf_f[i] = (grow < N) ? *(const float4*)&Af[(size_t)grow * 128 + 64 + j * 4]
                                 : make_float4(0.f, 0.f, 0.f, 0.f);
        }
    } else {
        const uint* Ab = (const uint*)Aptr;
#pragma unroll
        for (int i = 0; i < 4; i++) {
            int gi = tid + i * 256;
            int row = gi >> 3, c4 = (gi & 7) << 2;
            int grow = m0 + row;
            pf_u[i] = (grow < N) ? *(const uint4*)&Ab[(size_t)grow * 64 + 32 + c4]
                                 : make_uint4(0u, 0u, 0u, 0u);
        }
    }

    // ---- compute stage 0
#pragma unroll
    for (int kc = 0; kc < 2; kc++) {
        int ko = kc * 16 + quad * 4;
        short8 b[8];
#pragma unroll
        for (int nt = 0; nt < 8; nt++)
            b[nt] = *(short8*)&w_lds[(nt * 16 + lm) * SPAD + ko];
        short8 a0 = *(short8*)&a_lds[(wave * 32 + lm) * SPAD + ko];
        short8 a1 = *(short8*)&a_lds[(wave * 32 + 16 + lm) * SPAD + ko];
#pragma unroll
        for (int nt = 0; nt < 8; nt++) {
            acc[0][nt] = __builtin_amdgcn_mfma_f32_16x16x32_bf16(a0, b[nt], acc[0][nt], 0, 0, 0);
            acc[1][nt] = __builtin_amdgcn_mfma_f32_16x16x32_bf16(a1, b[nt], acc[1][nt], 0, 0, 0);
        }
    }
    __syncthreads();

    // ---- stage 1: regs -> LDS; W(ks=1) -> LDS
    if (F32A) {
#pragma unroll
        for (int i = 0; i < 8; i++) {
            int gi = tid + i * 256;
            int row = gi >> 4, j = gi & 15;
            uint2 o;
            o.x = f2bf(pf_f[i].x) | (f2bf(pf_f[i].y) << 16);
            o.y = f2bf(pf_f[i].z) | (f2bf(pf_f[i].w) << 16);
            *(uint2*)&a_lds[row * SPAD + j * 2] = o;
        }
    } else {
#pragma unroll
        for (int i = 0; i < 4; i++) {
            int gi = tid + i * 256;
            int row = gi >> 3, c4 = (gi & 7) << 2;
            *(uint4*)&a_lds[row * SPAD + c4] = pf_u[i];
        }
    }
#pragma unroll
    for (int i = 0; i < 4; i++) {
        int gi = tid + i * 256;
        int row = gi >> 3, c4 = (gi & 7) << 2;
        *(uint4*)&w_lds[row * SPAD + c4] = *(const uint4*)&Wt[(size_t)row * 64 + 32 + c4];
    }
    __syncthreads();

    // ---- compute stage 1
#pragma unroll
    for (int kc = 0; kc < 2; kc++) {
        int ko = kc * 16 + quad * 4;
        short8 b[8];
#pragma unroll
        for (int nt = 0; nt < 8; nt++)
            b[nt] = *(short8*)&w_lds[(nt * 16 + lm) * SPAD + ko];
        short8 a0 = *(short8*)&a_lds[(wave * 32 + lm) * SPAD + ko];
        short8 a1 = *(short8*)&a_lds[(wave * 32 + 16 + lm) * SPAD + ko];
#pragma unroll
        for (int nt = 0; nt < 8; nt++) {
            acc[0][nt] = __builtin_amdgcn_mfma_f32_16x16x32_bf16(a0, b[nt], acc[0][nt], 0, 0, 0);
            acc[1][nt] = __builtin_amdgcn_mfma_f32_16x16x32_bf16(a1, b[nt], acc[1][nt], 0, 0, 0);
        }
    }
    __syncthreads();

    // ---- epilogue: scale by dis, pack bf16, LDS bounce, coalesced store
    ushort* o_lds = (ushort*)lds;  // [128][132]
    float dv[2][4];
#pragma unroll
    for (int ms = 0; ms < 2; ms++)
#pragma unroll
        for (int r = 0; r < 4; r++) {
            int row = m0 + wave * 32 + ms * 16 + quad * 4 + r;
            dv[ms][r] = (row < N) ? dis[row] : 0.f;
        }
#pragma unroll
    for (int ms = 0; ms < 2; ms++)
#pragma unroll
        for (int nt = 0; nt < 8; nt++)
#pragma unroll
            for (int r = 0; r < 4; r++) {
                int row = wave * 32 + ms * 16 + quad * 4 + r;
                int col = nt * 16 + lm;
                o_lds[row * 132 + col] = (ushort)f2bf(acc[ms][nt][r] * dv[ms][r]);
            }
    __syncthreads();
#pragma unroll
    for (int i = 0; i < 16; i++) {
        int gi = tid + i * 256;
        int row = gi >> 5, c2 = gi & 31;
        int grow = m0 + row;
        if (grow < N) {
            uint2 v = *(uint2*)&lds[row * 66 + c2 * 2];
            *(uint2*)&U[(size_t)grow * 64 + c2 * 2] = v;
        }
    }
}

// ================= Aggregation v2: 16 lanes/edge, 4 edges per VMEM instr =================
__launch_bounds__(256)
__global__ void aggregate_kernel(const uint* __restrict__ U, const int* __restrict__ offs,
                                 const int* __restrict__ oend, const int* __restrict__ csr_src,
                                 const float* __restrict__ dis, const float* __restrict__ bias,
                                 uint* __restrict__ H, int N) {
    int wave = threadIdx.x >> 6;
    int lane = threadIdx.x & 63;
    int n = blockIdx.x * 4 + wave;
    if (n >= N) return;
    int g = lane >> 4, i16 = lane & 15;

    float a0 = 0.f, a1 = 0.f, a2 = 0.f, a3 = 0.f, a4 = 0.f, a5 = 0.f, a6 = 0.f, a7 = 0.f;
    int s = offs[n], e = oend[n];
    int j = s + g;
    for (; j + 12 < e; j += 16) {
        int s0 = csr_src[j], s1 = csr_src[j + 4], s2 = csr_src[j + 8], s3 = csr_src[j + 12];
        uint4 u0 = *(const uint4*)&U[(size_t)s0 * 64 + i16 * 4];
        uint4 u1 = *(const uint4*)&U[(size_t)s1 * 64 + i16 * 4];
        uint4 u2 = *(const uint4*)&U[(size_t)s2 * 64 + i16 * 4];
        uint4 u3 = *(const uint4*)&U[(size_t)s3 * 64 + i16 * 4];
        a0 += bf_lo(u0.x) + bf_lo(u1.x) + bf_lo(u2.x) + bf_lo(u3.x);
        a1 += bf_hi(u0.x) + bf_hi(u1.x) + bf_hi(u2.x) + bf_hi(u3.x);
        a2 += bf_lo(u0.y) + bf_lo(u1.y) + bf_lo(u2.y) + bf_lo(u3.y);
        a3 += bf_hi(u0.y) + bf_hi(u1.y) + bf_hi(u2.y) + bf_hi(u3.y);
        a4 += bf_lo(u0.z) + bf_lo(u1.z) + bf_lo(u2.z) + bf_lo(u3.z);
        a5 += bf_hi(u0.z) + bf_hi(u1.z) + bf_hi(u2.z) + bf_hi(u3.z);
        a6 += bf_lo(u0.w) + bf_lo(u1.w) + bf_lo(u2.w) + bf_lo(u3.w);
        a7 += bf_hi(u0.w) + bf_hi(u1.w) + bf_hi(u2.w) + bf_hi(u3.w);
    }
    for (; j < e; j += 4) {
        int s0 = csr_src[j];
        uint4 u = *(const uint4*)&U[(size_t)s0 * 64 + i16 * 4];
        a0 += bf_lo(u.x); a1 += bf_hi(u.x);
        a2 += bf_lo(u.y); a3 += bf_hi(u.y);
        a4 += bf_lo(u.z); a5 += bf_hi(u.z);
        a6 += bf_lo(u.w); a7 += bf_hi(u.w);
    }
    a0 += __shfl_xor(a0, 16); a0 += __shfl_xor(a0, 32);
    a1 += __shfl_xor(a1, 16); a1 += __shfl_xor(a1, 32);
    a2 += __shfl_xor(a2, 16); a2 += __shfl_xor(a2, 32);
    a3 += __shfl_xor(a3, 16); a3 += __shfl_xor(a3, 32);
    a4 += __shfl_xor(a4, 16); a4 += __shfl_xor(a4, 32);
    a5 += __shfl_xor(a5, 16); a5 += __shfl_xor(a5, 32);
    a6 += __shfl_xor(a6, 16); a6 += __shfl_xor(a6, 32);
    a7 += __shfl_xor(a7, 16); a7 += __shfl_xor(a7, 32);

    if (g == 0) {
        uint4 su = *(const uint4*)&U[(size_t)n * 64 + i16 * 4];
        a0 += bf_lo(su.x); a1 += bf_hi(su.x);
        a2 += bf_lo(su.y); a3 += bf_hi(su.y);
        a4 += bf_lo(su.z); a5 += bf_hi(su.z);
        a6 += bf_lo(su.w); a7 += bf_hi(su.w);
        float dn = dis[n];
        float4 b0 = *(const float4*)&bias[i16 * 8];
        float4 b1 = *(const float4*)&bias[i16 * 8 + 4];
        uint4 o;
        o.x = f2bf(fmaxf(fmaf(a0, dn, b0.x), 0.f)) | (f2bf(fmaxf(fmaf(a1, dn, b0.y), 0.f)) << 16);
        o.y = f2bf(fmaxf(fmaf(a2, dn, b0.z), 0.f)) | (f2bf(fmaxf(fmaf(a3, dn, b0.w), 0.f)) << 16);
        o.z = f2bf(fmaxf(fmaf(a4, dn, b1.x), 0.f)) | (f2bf(fmaxf(fmaf(a5, dn, b1.y), 0.f)) << 16);
        o.w = f2bf(fmaxf(fmaf(a6, dn, b1.z), 0.f)) | (f2bf(fmaxf(fmaf(a7, dn, b1.w), 0.f)) << 16);
        *(uint4*)&H[(size_t)n * 64 + i16 * 4] = o;
    }
}

// ================= Mean-pool per graph + FC (bf16 H) =================
__launch_bounds__(512)
__global__ void pool_fc_kernel(const uint* __restrict__ H, const int* __restrict__ batch,
                               const float* __restrict__ Wfc, const float* __restrict__ bfc,
                               float* __restrict__ out, int N) {
    __shared__ float2 red[512];
    int g = blockIdx.x;
    int t = threadIdx.x;
    int rid = t >> 6, lane = t & 63;

    int lo = 0, hi = N;
    while (lo < hi) { int mid = (lo + hi) >> 1; if (batch[mid] < g) lo = mid + 1; else hi = mid; }
    int st = lo;
    hi = N;
    while (lo < hi) { int mid = (lo + hi) >> 1; if (batch[mid] < g + 1) lo = mid + 1; else hi = mid; }
    int en = lo;

    float ax = 0.f, ay = 0.f;
    for (int r = st + rid; r < en; r += 8) {
        uint u = H[(size_t)r * 64 + lane];
        ax += bf_lo(u);
        ay += bf_hi(u);
    }
    red[t] = make_float2(ax, ay);
    __syncthreads();
    if (rid == 0) {
        float2 sv = red[lane];
#pragma unroll
        for (int i = 1; i < 8; i++) { sv.x += red[i * 64 + lane].x; sv.y += red[i * 64 + lane].y; }
        float cnt = fmaxf((float)(en - st), 1.0f);
        float p = (sv.x / cnt) * Wfc[lane * 2] + (sv.y / cnt) * Wfc[lane * 2 + 1];
        for (int off = 32; off > 0; off >>= 1) p += __shfl_down(p, off);
        if (lane == 0) out[g] = p + bfc[0];
    }
}

extern "C" void kernel_launch(void* const* d_in, const int* in_sizes, int n_in,
                              void* d_out, int out_size, void* d_ws, size_t ws_size,
                              hipStream_t stream) {
    const float* x   = (const float*)d_in[0];
    const int* eidx  = (const int*)d_in[1];
    const int* batch = (const int*)d_in[2];
    const float* W1  = (const float*)d_in[3];
    const float* b1  = (const float*)d_in[4];
    const float* W2  = (const float*)d_in[5];
    const float* b2  = (const float*)d_in[6];
    const float* W3  = (const float*)d_in[7];
    const float* b3  = (const float*)d_in[8];
    const float* Wfc = (const float*)d_in[9];
    const float* bfc = (const float*)d_in[10];
    float* out = (float*)d_out;

    int N = in_sizes[2];
    int E = in_sizes[1] / 2;
    int G = out_size;
    int NB = (N + 511) >> 9;                   // <= 256
    int CAP = E / NB + 1536;                   // per-bucket window (~16 sigma slack)

    const int* src = eidx;
    const int* dst = eidx + E;

    char* ws = (char*)d_ws;
    size_t off = 0;
    auto alloc = [&](size_t bytes) -> void* {
        void* p = ws + off;
        off += (bytes + 255) & ~(size_t)255;
        return p;
    };
    size_t winsz = (size_t)NB * CAP;
    uint* Ua     = (uint*)alloc((size_t)N * 64 * sizeof(uint));   // bf16 [N,128]
    uint* Ub     = (uint*)alloc((size_t)N * 64 * sizeof(uint));   // bf16 [N,128]
    uint* Wt1    = (uint*)alloc(8192 * sizeof(uint));
    uint* Wt2    = (uint*)alloc(8192 * sizeof(uint));
    uint* Wt3    = (uint*)alloc(8192 * sizeof(uint));
    float* dis   = (float*)alloc((size_t)N * sizeof(float));
    int* offs    = (int*)alloc((size_t)N * sizeof(int));
    int* oend    = (int*)alloc((size_t)N * sizeof(int));
    int* csr     = (int*)alloc(winsz * sizeof(int));
    uint* binned = (uint*)alloc(winsz * sizeof(uint));
    int* cursor  = (int*)alloc(256 * sizeof(int));
    (void)ws_size; (void)n_in;

    int cb = (E + CHUNK - 1) / CHUNK;

    setup_kernel<<<97, 256, 0, stream>>>(W1, W2, W3, Wt1, Wt2, Wt3, cursor, NB, CAP);
    bin_kernel<<<cb, 256, 0, stream>>>(src, dst, cursor, binned, E);
    bucket_build_kernel<<<NB, 256, 0, stream>>>(binned, cursor, offs, oend, csr, dis, N, CAP);

    int gb = (N + 127) / 128;
    int ab = (N + 3) / 4;

    gemm_mfma_kernel<true><<<gb, 256, 0, stream>>>(x, Wt1, dis, Ua, N);
    aggregate_kernel<<<ab, 256, 0, stream>>>(Ua, offs, oend, csr, dis, b1, Ub, N);
    gemm_mfma_kernel<false><<<gb, 256, 0, stream>>>(Ub, Wt2, dis, Ua, N);
    aggregate_kernel<<<ab, 256, 0, stream>>>(Ua, offs, oend, csr, dis, b2, Ub, N);
    gemm_mfma_kernel<false><<<gb, 256, 0, stream>>>(Ub, Wt3, dis, Ua, N);
    aggregate_kernel<<<ab, 256, 0, stream>>>(Ua, offs, oend, csr, dis, b3, Ub, N);
    pool_fc_kernel<<<G, 512, 0, stream>>>(Ub, batch, Wfc, bfc, out, N);
}